// Round 2
// baseline (793.822 us; speedup 1.0000x reference)
//
#include <hip/hip_runtime.h>

#define BN_EPS 1e-3f

static constexpr int B_TASKS = 64;
static constexpr int E_EX    = 64;

// ---------------------------------------------------------------------------
// conv1_stats: x[64,64,28,28,1] * k1[64,3,3,1,64] -> per-channel sum/sumsq of
// relu(conv1) into stats[0..127].  NO y1 materialization (recomputed in the
// fused conv2 kernel).  One block per (b,e) image, 256 threads.
// ---------------------------------------------------------------------------
__global__ __launch_bounds__(256) void conv1_stats_kernel(
    const float* __restrict__ x, const float* __restrict__ k1,
    float* __restrict__ stats)
{
  __shared__ float xin[784];
  __shared__ float w[576];
  __shared__ float red[256];

  const int be  = blockIdx.x;
  const int b   = be >> 6;
  const int tid = threadIdx.x;

  for (int i = tid; i < 784; i += 256) xin[i] = x[(size_t)be * 784 + i];
  for (int i = tid; i < 576; i += 256) w[i]   = k1[(size_t)b * 576 + i];
  __syncthreads();

  const int c  = tid & 63;
  const int p4 = tid >> 6;

  float sum = 0.f, ss = 0.f;
  for (int pix = p4; pix < 196; pix += 4) {
    const int oy = pix / 14, ox = pix % 14;
    const int iy0 = 2 * oy - 1, ix0 = 2 * ox - 1;
    float acc = 0.f;
#pragma unroll
    for (int dy = 0; dy < 3; ++dy) {
      const int iy = iy0 + dy;
      if ((unsigned)iy >= 28u) continue;
#pragma unroll
      for (int dx = 0; dx < 3; ++dx) {
        const int ix = ix0 + dx;
        if ((unsigned)ix >= 28u) continue;
        acc = fmaf(xin[iy * 28 + ix], w[(dy * 3 + dx) * 64 + c], acc);
      }
    }
    const float v = fmaxf(acc, 0.f);
    sum += v;
    ss  = fmaf(v, v, ss);
  }

  red[tid] = sum;
  __syncthreads();
  if (tid < 64)
    atomicAdd(&stats[tid], red[tid] + red[tid + 64] + red[tid + 128] + red[tid + 192]);
  __syncthreads();
  red[tid] = ss;
  __syncthreads();
  if (tid < 64)
    atomicAdd(&stats[64 + tid], red[tid] + red[tid + 64] + red[tid + 128] + red[tid + 192]);
}

// ---------------------------------------------------------------------------
// Fused conv1+conv2: one block per (b,e).  Recomputes BN1(relu(conv1(x)))
// per K-slice from LDS-resident x/k1 (no y1 in HBM), then implicit-GEMM
// against k2.  Output: raw post-ReLU y2 [b][e][7][7][64] + stats atomics.
// Tile: 49 pixel-rows (padded to 64) x 64 couts, K = 9 slices x 64 cin.
// ---------------------------------------------------------------------------
__global__ __launch_bounds__(256) void conv2_fused_kernel(
    const float* __restrict__ x, const float* __restrict__ k1,
    const float* __restrict__ k2, const float* __restrict__ statsIn,
    float invN, float* __restrict__ out, float* __restrict__ statsOut)
{
  __shared__ float xin[784];
  __shared__ float w1[576];
  __shared__ float At[64 * 68];   // [cin][row], padded stride 68
  __shared__ float Bs[64 * 64];   // [cin][cout]
  __shared__ float s1[64], t1[64];
  __shared__ float redsum[64], redss[64];

  const int be  = blockIdx.x;
  const int b   = be >> 6;
  const int tid = threadIdx.x;

  for (int i = tid; i < 784; i += 256) xin[i] = x[(size_t)be * 784 + i];
  for (int i = tid; i < 576; i += 256) w1[i]  = k1[(size_t)b * 576 + i];
  if (tid < 64) {
    const float m   = statsIn[tid] * invN;
    const float var = fmaf(-m, m, statsIn[64 + tid] * invN);
    const float s   = rsqrtf(var + BN_EPS);
    s1[tid] = s;
    t1[tid] = -m * s;
    redsum[tid] = 0.f;
    redss[tid]  = 0.f;
  }

  // loader mapping: row li (output pixel of 7x7, valid < 49), 16 cins at lj0
  const int li  = tid >> 2;
  const int lj0 = (tid & 3) * 16;
  const int oy  = li / 7, ox = li % 7;

  // compute mapping: 4 rows x 4 couts per thread
  const int i0 = (tid >> 4) * 4;
  const int c0 = (tid & 15) * 4;

  float acc[4][4] = {};

  __syncthreads();  // xin/w1/s1/t1 ready

#pragma unroll
  for (int ky = 0; ky < 3; ++ky) {
#pragma unroll
    for (int kx = 0; kx < 3; ++kx) {
      // ---- recompute A tile: BN1(relu(conv1)) at layer-1 pixel (iy,ix) ----
      const int iy = 2 * oy - 1 + ky;   // coords in 14x14
      const int ix = 2 * ox - 1 + kx;
      const bool ok = (li < 49) && ((unsigned)iy < 14u) && ((unsigned)ix < 14u);
      float xv[9];
      if (ok) {
        const int y0 = 2 * iy - 1, x0 = 2 * ix - 1;
#pragma unroll
        for (int dy = 0; dy < 3; ++dy) {
#pragma unroll
          for (int dx = 0; dx < 3; ++dx) {
            const int yy = y0 + dy, xx = x0 + dx;
            xv[dy * 3 + dx] =
                ((unsigned)yy < 28u && (unsigned)xx < 28u) ? xin[yy * 28 + xx] : 0.f;
          }
        }
      }
#pragma unroll
      for (int q = 0; q < 16; ++q) {
        const int c = lj0 + q;
        float a = 0.f;
        if (ok) {
          float a1 = 0.f;
#pragma unroll
          for (int t = 0; t < 9; ++t) a1 = fmaf(xv[t], w1[t * 64 + c], a1);
          a = fmaf(fmaxf(a1, 0.f), s1[c], t1[c]);
        }
        At[c * 68 + li] = a;
      }
      // ---- stage B tile (one (ky,kx) slice of k2, 64x64) ----
      {
        const float* wsl = k2 + ((size_t)b * 9 + (ky * 3 + kx)) * 4096 + tid * 16;
#pragma unroll
        for (int q = 0; q < 4; ++q)
          *(float4*)&Bs[tid * 16 + q * 4] = *(const float4*)(wsl + q * 4);
      }
      __syncthreads();

      // ---- 64-deep outer-product accumulate ----
#pragma unroll 8
      for (int cin = 0; cin < 64; ++cin) {
        const float4 a  = *(const float4*)&At[cin * 68 + i0];
        const float4 bv = *(const float4*)&Bs[cin * 64 + c0];
        acc[0][0] = fmaf(a.x, bv.x, acc[0][0]);
        acc[0][1] = fmaf(a.x, bv.y, acc[0][1]);
        acc[0][2] = fmaf(a.x, bv.z, acc[0][2]);
        acc[0][3] = fmaf(a.x, bv.w, acc[0][3]);
        acc[1][0] = fmaf(a.y, bv.x, acc[1][0]);
        acc[1][1] = fmaf(a.y, bv.y, acc[1][1]);
        acc[1][2] = fmaf(a.y, bv.z, acc[1][2]);
        acc[1][3] = fmaf(a.y, bv.w, acc[1][3]);
        acc[2][0] = fmaf(a.z, bv.x, acc[2][0]);
        acc[2][1] = fmaf(a.z, bv.y, acc[2][1]);
        acc[2][2] = fmaf(a.z, bv.z, acc[2][2]);
        acc[2][3] = fmaf(a.z, bv.w, acc[2][3]);
        acc[3][0] = fmaf(a.w, bv.x, acc[3][0]);
        acc[3][1] = fmaf(a.w, bv.y, acc[3][1]);
        acc[3][2] = fmaf(a.w, bv.z, acc[3][2]);
        acc[3][3] = fmaf(a.w, bv.w, acc[3][3]);
      }
      __syncthreads();
    }
  }

  // ---- epilogue: ReLU, store valid rows, per-channel stats ----
  float cs[4] = {0.f, 0.f, 0.f, 0.f};
  float css[4] = {0.f, 0.f, 0.f, 0.f};
#pragma unroll
  for (int r = 0; r < 4; ++r) {
    const int row = i0 + r;
    if (row < 49) {
      float4 o4;
      o4.x = fmaxf(acc[r][0], 0.f);
      o4.y = fmaxf(acc[r][1], 0.f);
      o4.z = fmaxf(acc[r][2], 0.f);
      o4.w = fmaxf(acc[r][3], 0.f);
      cs[0] += o4.x; css[0] = fmaf(o4.x, o4.x, css[0]);
      cs[1] += o4.y; css[1] = fmaf(o4.y, o4.y, css[1]);
      cs[2] += o4.z; css[2] = fmaf(o4.z, o4.z, css[2]);
      cs[3] += o4.w; css[3] = fmaf(o4.w, o4.w, css[3]);
      *(float4*)&out[((size_t)be * 49 + row) * 64 + c0] = o4;
    }
  }
#pragma unroll
  for (int cc = 0; cc < 4; ++cc) {
    atomicAdd(&redsum[c0 + cc], cs[cc]);
    atomicAdd(&redss[c0 + cc], css[cc]);
  }
  __syncthreads();
  if (tid < 64) {
    atomicAdd(&statsOut[tid], redsum[tid]);
    atomicAdd(&statsOut[64 + tid], redss[tid]);
  }
}

// ---------------------------------------------------------------------------
// Generic conv block (layers 3..4) as implicit GEMM.
// in: raw post-ReLU [b][e][Hin][Hin][64]; statsIn folded into A-tile load.
// out: raw post-ReLU [b][e][Hout][Hout][64] + stats atomics.
// ---------------------------------------------------------------------------
template <int Hin, int Hout>
__global__ __launch_bounds__(256) void conv_bn_kernel(
    const float* __restrict__ in, const float* __restrict__ w,
    const float* __restrict__ statsIn, float invN,
    float* __restrict__ out, float* __restrict__ statsOut)
{
  constexpr int M   = E_EX * Hout * Hout;  // rows per task
  constexpr int BPT = M / 64;              // blocks per task

  __shared__ float At[64 * 68];   // [cin][row], padded stride 68
  __shared__ float Bs[64 * 64];   // [cin][cout]
  __shared__ float sArr[64], tArr[64];
  __shared__ float redsum[64], redss[64];

  const int tid = threadIdx.x;
  const int b   = blockIdx.x / BPT;
  const int r0  = (blockIdx.x % BPT) * 64;

  if (tid < 64) {
    const float m   = statsIn[tid] * invN;
    const float var = fmaf(-m, m, statsIn[64 + tid] * invN);
    const float s   = rsqrtf(var + BN_EPS);
    sArr[tid] = s;
    tArr[tid] = -m * s;
    redsum[tid] = 0.f;
    redss[tid]  = 0.f;
  }

  const int li  = tid >> 2;
  const int lj0 = (tid & 3) * 16;
  const int pid = r0 + li;
  const int e   = pid / (Hout * Hout);
  const int p   = pid % (Hout * Hout);
  const int oy  = p / Hout, ox = p % Hout;

  const int i0 = (tid >> 4) * 4;
  const int c0 = (tid & 15) * 4;

  float acc[4][4] = {};

  __syncthreads();  // sArr/tArr ready

#pragma unroll
  for (int ky = 0; ky < 3; ++ky) {
#pragma unroll
    for (int kx = 0; kx < 3; ++kx) {
      const int iy = 2 * oy - 1 + ky;
      const int ix = 2 * ox - 1 + kx;
      const bool ok = ((unsigned)iy < (unsigned)Hin) && ((unsigned)ix < (unsigned)Hin);
      const float* src =
          in + ((size_t)((b * E_EX + e) * Hin * Hin + iy * Hin + ix)) * 64 + lj0;
#pragma unroll
      for (int q = 0; q < 4; ++q) {
        const int cb = lj0 + q * 4;
        float a0, a1, a2, a3;
        if (ok) {
          const float4 v = *(const float4*)(src + q * 4);
          a0 = fmaf(v.x, sArr[cb + 0], tArr[cb + 0]);
          a1 = fmaf(v.y, sArr[cb + 1], tArr[cb + 1]);
          a2 = fmaf(v.z, sArr[cb + 2], tArr[cb + 2]);
          a3 = fmaf(v.w, sArr[cb + 3], tArr[cb + 3]);
        } else {
          a0 = a1 = a2 = a3 = 0.f;
        }
        At[(cb + 0) * 68 + li] = a0;
        At[(cb + 1) * 68 + li] = a1;
        At[(cb + 2) * 68 + li] = a2;
        At[(cb + 3) * 68 + li] = a3;
      }
      {
        const float* wsl = w + ((size_t)b * 9 + (ky * 3 + kx)) * 4096 + tid * 16;
#pragma unroll
        for (int q = 0; q < 4; ++q)
          *(float4*)&Bs[tid * 16 + q * 4] = *(const float4*)(wsl + q * 4);
      }
      __syncthreads();

#pragma unroll 8
      for (int cin = 0; cin < 64; ++cin) {
        const float4 a  = *(const float4*)&At[cin * 68 + i0];
        const float4 bv = *(const float4*)&Bs[cin * 64 + c0];
        acc[0][0] = fmaf(a.x, bv.x, acc[0][0]);
        acc[0][1] = fmaf(a.x, bv.y, acc[0][1]);
        acc[0][2] = fmaf(a.x, bv.z, acc[0][2]);
        acc[0][3] = fmaf(a.x, bv.w, acc[0][3]);
        acc[1][0] = fmaf(a.y, bv.x, acc[1][0]);
        acc[1][1] = fmaf(a.y, bv.y, acc[1][1]);
        acc[1][2] = fmaf(a.y, bv.z, acc[1][2]);
        acc[1][3] = fmaf(a.y, bv.w, acc[1][3]);
        acc[2][0] = fmaf(a.z, bv.x, acc[2][0]);
        acc[2][1] = fmaf(a.z, bv.y, acc[2][1]);
        acc[2][2] = fmaf(a.z, bv.z, acc[2][2]);
        acc[2][3] = fmaf(a.z, bv.w, acc[2][3]);
        acc[3][0] = fmaf(a.w, bv.x, acc[3][0]);
        acc[3][1] = fmaf(a.w, bv.y, acc[3][1]);
        acc[3][2] = fmaf(a.w, bv.z, acc[3][2]);
        acc[3][3] = fmaf(a.w, bv.w, acc[3][3]);
      }
      __syncthreads();
    }
  }

  float cs[4] = {0.f, 0.f, 0.f, 0.f};
  float css[4] = {0.f, 0.f, 0.f, 0.f};
#pragma unroll
  for (int r = 0; r < 4; ++r) {
    float4 o4;
    o4.x = fmaxf(acc[r][0], 0.f);
    o4.y = fmaxf(acc[r][1], 0.f);
    o4.z = fmaxf(acc[r][2], 0.f);
    o4.w = fmaxf(acc[r][3], 0.f);
    cs[0] += o4.x; css[0] = fmaf(o4.x, o4.x, css[0]);
    cs[1] += o4.y; css[1] = fmaf(o4.y, o4.y, css[1]);
    cs[2] += o4.z; css[2] = fmaf(o4.z, o4.z, css[2]);
    cs[3] += o4.w; css[3] = fmaf(o4.w, o4.w, css[3]);
    *(float4*)&out[((size_t)b * M + (r0 + i0 + r)) * 64 + c0] = o4;
  }
#pragma unroll
  for (int cc = 0; cc < 4; ++cc) {
    atomicAdd(&redsum[c0 + cc], cs[cc]);
    atomicAdd(&redss[c0 + cc], css[cc]);
  }
  __syncthreads();
  if (tid < 64) {
    atomicAdd(&statsOut[tid], redsum[tid]);
    atomicAdd(&statsOut[64 + tid], redss[tid]);
  }
}

// ---------------------------------------------------------------------------
// readout: feat = BN(maxpool(y4)) (max commutes with positive affine), then
// per-task matmul feat[64,64] @ w_ro[64,20].  One block per task.
// ---------------------------------------------------------------------------
__global__ __launch_bounds__(256) void readout_kernel(
    const float* __restrict__ y4, const float* __restrict__ w_ro,
    const float* __restrict__ statsIn, float invN, float* __restrict__ outp)
{
  __shared__ float wl[64 * 20];
  __shared__ float feat[64 * 64];  // [c][e]
  __shared__ float sArr[64], tArr[64];

  const int b = blockIdx.x;
  const int tid = threadIdx.x;

  if (tid < 64) {
    const float m   = statsIn[tid] * invN;
    const float var = fmaf(-m, m, statsIn[64 + tid] * invN);
    const float s   = rsqrtf(var + BN_EPS);
    sArr[tid] = s;
    tArr[tid] = -m * s;
  }
  for (int i = tid; i < 1280; i += 256) wl[i] = w_ro[(size_t)b * 1280 + i];
  __syncthreads();

  {
    const int e = tid & 63;
    for (int c = tid >> 6; c < 64; c += 4) {
      const float* p4 = y4 + ((size_t)(b * 64 + e) * 4) * 64 + c;
      const float v = fmaxf(fmaxf(p4[0], p4[64]), fmaxf(p4[128], p4[192]));
      feat[c * 64 + e] = fmaf(v, sArr[c], tArr[c]);
    }
  }
  __syncthreads();

  const int e  = tid >> 2;
  const int og = (tid & 3) * 5;
  float acc[5] = {0.f, 0.f, 0.f, 0.f, 0.f};
  for (int c = 0; c < 64; ++c) {
    const float f = feat[c * 64 + e];
#pragma unroll
    for (int j = 0; j < 5; ++j) acc[j] = fmaf(f, wl[c * 20 + og + j], acc[j]);
  }
#pragma unroll
  for (int j = 0; j < 5; ++j)
    outp[((size_t)b * 64 + e) * 20 + og + j] = acc[j];
}

// ---------------------------------------------------------------------------
extern "C" void kernel_launch(void* const* d_in, const int* in_sizes, int n_in,
                              void* d_out, int out_size, void* d_ws, size_t ws_size,
                              hipStream_t stream) {
  (void)in_sizes; (void)n_in; (void)out_size; (void)ws_size;
  const float* x   = (const float*)d_in[0];
  const float* k1  = (const float*)d_in[1];
  const float* k2  = (const float*)d_in[2];
  const float* k3  = (const float*)d_in[3];
  const float* k4  = (const float*)d_in[4];
  const float* wro = (const float*)d_in[5];
  float* out = (float*)d_out;
  float* ws  = (float*)d_ws;

  // workspace: stats[512] + y2[12.85M] + y3[4.19M] + y4[1.05M]  = 72.4 MB
  float* stats = ws;
  float* y2 = ws + 512;                    // 64*64*49*64 = 12,845,056
  float* y3 = y2 + (size_t)12845056;       // 64*64*16*64 =  4,194,304
  float* y4 = y3 + (size_t)4194304;        // 64*64*4*64  =  1,048,576

  hipMemsetAsync(stats, 0, 512 * sizeof(float), stream);

  conv1_stats_kernel<<<64 * 64, 256, 0, stream>>>(x, k1, stats);
  conv2_fused_kernel<<<64 * 64, 256, 0, stream>>>(
      x, k1, k2, stats, 1.f / 802816.f, y2, stats + 128);
  conv_bn_kernel<7, 4><<<64 * 16, 256, 0, stream>>>(
      y2, k3, stats + 128, 1.f / 200704.f, y3, stats + 256);
  conv_bn_kernel<4, 2><<<64 * 4, 256, 0, stream>>>(
      y3, k4, stats + 256, 1.f / 65536.f, y4, stats + 384);
  readout_kernel<<<64, 256, 0, stream>>>(y4, wro, stats + 384, 1.f / 16384.f, out);
}

// Round 3
// 393.656 us; speedup vs baseline: 2.0165x; 2.0165x over previous
//
#include <hip/hip_runtime.h>

#define BN_EPS 1e-3f

typedef __attribute__((ext_vector_type(8))) short bf16x8;
typedef __attribute__((ext_vector_type(16))) float floatx16;

__device__ __forceinline__ unsigned short f2bf(float f) {
  unsigned u = __float_as_uint(f);
  u += 0x7fffu + ((u >> 16) & 1u);   // RNE
  return (unsigned short)(u >> 16);
}
__device__ __forceinline__ float bf2f(unsigned short h) {
  return __uint_as_float(((unsigned)h) << 16);
}

// ---------------------------------------------------------------------------
// prep: k2/k3/k4 fp32 [b][s][cin][cout] -> bf16 transposed [b][s][cout][cin].
// 192 blocks (3 layers x 64 tasks), 9 slices each, LDS bounce for coalescing.
// ---------------------------------------------------------------------------
__global__ __launch_bounds__(256) void prep_weights_kernel(
    const float* __restrict__ k2, const float* __restrict__ k3,
    const float* __restrict__ k4, unsigned short* __restrict__ k2t,
    unsigned short* __restrict__ k3t, unsigned short* __restrict__ k4t)
{
  __shared__ float T[64 * 68];
  const int blk = blockIdx.x;
  const int l = blk >> 6;
  const int b = blk & 63;
  const float* src = (l == 0 ? k2 : l == 1 ? k3 : k4) + (size_t)b * 9 * 4096;
  unsigned short* dst = (l == 0 ? k2t : l == 1 ? k3t : k4t) + (size_t)b * 9 * 4096;
  const int tid = threadIdx.x;
  const int cin = tid >> 2, q0 = (tid & 3) * 16;
  const int cout = tid >> 2, ci0 = (tid & 3) * 16;

  for (int s = 0; s < 9; ++s) {
    const float* ss = src + s * 4096;
#pragma unroll
    for (int q = 0; q < 16; q += 4) {
      float4 v = *(const float4*)(ss + cin * 64 + q0 + q);
      T[(q0 + q + 0) * 68 + cin] = v.x;
      T[(q0 + q + 1) * 68 + cin] = v.y;
      T[(q0 + q + 2) * 68 + cin] = v.z;
      T[(q0 + q + 3) * 68 + cin] = v.w;
    }
    __syncthreads();
    alignas(16) unsigned short tmp[16];
#pragma unroll
    for (int j = 0; j < 16; ++j) tmp[j] = f2bf(T[cout * 68 + ci0 + j]);
    *(uint4*)(dst + s * 4096 + cout * 64 + ci0)     = *(uint4*)&tmp[0];
    *(uint4*)(dst + s * 4096 + cout * 64 + ci0 + 8) = *(uint4*)&tmp[8];
    __syncthreads();
  }
}

// ---------------------------------------------------------------------------
// conv1_stats: per-channel sum/sumsq of relu(conv1(x)) -> stats[0..127].
// ---------------------------------------------------------------------------
__global__ __launch_bounds__(256) void conv1_stats_kernel(
    const float* __restrict__ x, const float* __restrict__ k1,
    float* __restrict__ stats)
{
  __shared__ float xin[784];
  __shared__ float w[576];
  __shared__ float red[256];

  const int be = blockIdx.x;
  const int b  = be >> 6;
  const int tid = threadIdx.x;

  for (int i = tid; i < 784; i += 256) xin[i] = x[(size_t)be * 784 + i];
  for (int i = tid; i < 576; i += 256) w[i]   = k1[(size_t)b * 576 + i];
  __syncthreads();

  const int c = tid & 63;
  float sum = 0.f, ss = 0.f;
  for (int pix = tid >> 6; pix < 196; pix += 4) {
    const int oy = pix / 14, ox = pix % 14;
    const int iy0 = 2 * oy - 1, ix0 = 2 * ox - 1;
    float acc = 0.f;
#pragma unroll
    for (int dy = 0; dy < 3; ++dy) {
      const int iy = iy0 + dy;
      if ((unsigned)iy >= 28u) continue;
#pragma unroll
      for (int dx = 0; dx < 3; ++dx) {
        const int ix = ix0 + dx;
        if ((unsigned)ix >= 28u) continue;
        acc = fmaf(xin[iy * 28 + ix], w[(dy * 3 + dx) * 64 + c], acc);
      }
    }
    const float v = fmaxf(acc, 0.f);
    sum += v;
    ss  = fmaf(v, v, ss);
  }

  red[tid] = sum;
  __syncthreads();
  if (tid < 64)
    atomicAdd(&stats[tid], red[tid] + red[tid + 64] + red[tid + 128] + red[tid + 192]);
  __syncthreads();
  red[tid] = ss;
  __syncthreads();
  if (tid < 64)
    atomicAdd(&stats[64 + tid], red[tid] + red[tid + 64] + red[tid + 128] + red[tid + 192]);
}

// ---------------------------------------------------------------------------
// conv2 MFMA: one block per (b,e).  Build BN1(relu(conv1)) 14x14x64 bf16 map
// once in LDS (15x15 zero-padded, pixel stride 72 bf16), then 32x32x16 bf16
// MFMA implicit GEMM vs k2t.  y2 bf16 out + stats.
// ---------------------------------------------------------------------------
__global__ __launch_bounds__(256) void conv2_mfma_kernel(
    const float* __restrict__ x, const float* __restrict__ k1,
    const unsigned short* __restrict__ k2t, const float* __restrict__ statsIn,
    float invN, unsigned short* __restrict__ y2, float* __restrict__ statsOut)
{
  __shared__ float xin[784];
  __shared__ float w1[576];
  __shared__ float s1[64], t1[64];
  __shared__ float redsum[64], redss[64];
  __shared__ __align__(16) unsigned short mapS[225 * 72];  // 32400 B
  __shared__ __align__(16) unsigned short BtS[64 * 72];    //  9216 B

  const int be = blockIdx.x, b = be >> 6, tid = threadIdx.x;
  const int lane = tid & 63, wave = tid >> 6;

  for (int i = tid; i < 784; i += 256) xin[i] = x[(size_t)be * 784 + i];
  for (int i = tid; i < 576; i += 256) w1[i] = k1[(size_t)b * 576 + i];
  if (tid < 64) {
    const float m = statsIn[tid] * invN;
    const float var = fmaf(-m, m, statsIn[64 + tid] * invN);
    const float s = rsqrtf(var + BN_EPS);
    s1[tid] = s; t1[tid] = -m * s;
    redsum[tid] = 0.f; redss[tid] = 0.f;
  }
  for (int i = tid; i < 225 * 36; i += 256) ((unsigned*)mapS)[i] = 0u;
  __syncthreads();

  // build interior: 196 pixels x 64 ch
  {
    const int c0 = (tid & 3) * 16;
    for (int p = tid >> 2; p < 196; p += 64) {
      const int iy = p / 14, ix = p % 14;
      const int y0 = 2 * iy - 1, x0 = 2 * ix - 1;
      float xv[9];
#pragma unroll
      for (int dy = 0; dy < 3; ++dy)
#pragma unroll
        for (int dx = 0; dx < 3; ++dx) {
          const int yy = y0 + dy, xx = x0 + dx;
          xv[dy * 3 + dx] =
              ((unsigned)yy < 28u && (unsigned)xx < 28u) ? xin[yy * 28 + xx] : 0.f;
        }
      alignas(16) unsigned short tmp[16];
#pragma unroll
      for (int j = 0; j < 16; ++j) {
        const int c = c0 + j;
        float a = 0.f;
#pragma unroll
        for (int t = 0; t < 9; ++t) a = fmaf(xv[t], w1[t * 64 + c], a);
        tmp[j] = f2bf(fmaf(fmaxf(a, 0.f), s1[c], t1[c]));
      }
      unsigned short* dp = &mapS[((iy + 1) * 15 + (ix + 1)) * 72 + c0];
      *(uint4*)dp       = *(uint4*)&tmp[0];
      *(uint4*)(dp + 8) = *(uint4*)&tmp[8];
    }
  }
  __syncthreads();

  const int mi = wave & 1, ni = wave >> 1;
  const int m0 = mi * 32, n0 = ni * 32;
  const int lrow = m0 + (lane & 31);
  const int kq = (lane >> 5) * 8;
  const bool rowValid = lrow < 49;
  const int oy = rowValid ? lrow / 7 : 0;
  const int ox = rowValid ? lrow % 7 : 0;

  floatx16 acc;
#pragma unroll
  for (int r = 0; r < 16; ++r) acc[r] = 0.f;

  for (int s = 0; s < 9; ++s) {
    {  // stage Bt slice (bf16 [cout][cin] -> LDS stride 72)
      const unsigned short* g = k2t + ((size_t)b * 9 + s) * 4096;
      const int cout = tid >> 2, cc0 = (tid & 3) * 16;
      uint4 v0 = *(const uint4*)(g + cout * 64 + cc0);
      uint4 v1 = *(const uint4*)(g + cout * 64 + cc0 + 8);
      *(uint4*)&BtS[cout * 72 + cc0]     = v0;
      *(uint4*)&BtS[cout * 72 + cc0 + 8] = v1;
    }
    __syncthreads();
    const int ky = s / 3, kx = s - 3 * ky;
    int pix = 0;
    if (rowValid) {
      const int iy = 2 * oy - 1 + ky, ix = 2 * ox - 1 + kx;
      pix = (iy + 1) * 15 + (ix + 1);   // always in [0,224]; borders are zeros
    }
    const unsigned short* ap = &mapS[pix * 72 + kq];
    const unsigned short* bp = &BtS[(n0 + (lane & 31)) * 72 + kq];
#pragma unroll
    for (int st = 0; st < 4; ++st) {
      bf16x8 af = *(const bf16x8*)(ap + st * 16);
      bf16x8 bv = *(const bf16x8*)(bp + st * 16);
      acc = __builtin_amdgcn_mfma_f32_32x32x16_bf16(af, bv, acc, 0, 0, 0);
    }
    __syncthreads();
  }

  // epilogue: C/D layout col=lane&31, row=(reg&3)+8*(reg>>2)+4*(lane>>5)
  const int col = n0 + (lane & 31);
  const int rbase = m0 + 4 * (lane >> 5);
  float ls = 0.f, lss = 0.f;
#pragma unroll
  for (int r = 0; r < 16; ++r) {
    const int row = rbase + (r & 3) + 8 * (r >> 2);
    const float v = fmaxf(acc[r], 0.f);
    if (row < 49) {
      y2[((size_t)be * 49 + row) * 64 + col] = f2bf(v);
      ls += v; lss = fmaf(v, v, lss);
    }
  }
  atomicAdd(&redsum[col], ls);
  atomicAdd(&redss[col], lss);
  __syncthreads();
  if (tid < 64) {
    atomicAdd(&statsOut[tid], redsum[tid]);
    atomicAdd(&statsOut[64 + tid], redss[tid]);
  }
}

// ---------------------------------------------------------------------------
// Layers 3/4 MFMA: block = (b, G examples), M = G*Hout^2 = 64 rows, N=64,
// K=576.  Per-slice A staging from bf16 y_in with BN affine folded in.
// ---------------------------------------------------------------------------
template <int Hin, int Hout, int G>
__global__ __launch_bounds__(256) void conv_mfma_kernel(
    const unsigned short* __restrict__ yin, const unsigned short* __restrict__ wt,
    const float* __restrict__ statsIn, float invN,
    unsigned short* __restrict__ yout, float* __restrict__ statsOut)
{
  __shared__ __align__(16) unsigned short AS[64 * 72];
  __shared__ __align__(16) unsigned short BtS[64 * 72];
  __shared__ float s1[64], t1[64], redsum[64], redss[64];

  constexpr int BPT = 64 / G;
  const int b  = blockIdx.x / BPT;
  const int e0 = (blockIdx.x % BPT) * G;
  const int tid = threadIdx.x, lane = tid & 63, wave = tid >> 6;

  if (tid < 64) {
    const float m = statsIn[tid] * invN;
    const float var = fmaf(-m, m, statsIn[64 + tid] * invN);
    const float s = rsqrtf(var + BN_EPS);
    s1[tid] = s; t1[tid] = -m * s;
    redsum[tid] = 0.f; redss[tid] = 0.f;
  }
  __syncthreads();

  // A-staging mapping: row li, 16 cins at ci0
  const int li  = tid & 63;
  const int ci0 = (tid >> 6) * 16;
  const int e_l = li / (Hout * Hout);
  const int pp  = li % (Hout * Hout);
  const int oy = pp / Hout, ox = pp % Hout;

  const int mi = wave & 1, ni = wave >> 1;
  const int m0 = mi * 32, n0 = ni * 32;
  const int arow = m0 + (lane & 31);
  const int kq = (lane >> 5) * 8;

  floatx16 acc;
#pragma unroll
  for (int r = 0; r < 16; ++r) acc[r] = 0.f;

  for (int s = 0; s < 9; ++s) {
    const int ky = s / 3, kx = s - 3 * ky;
    {  // stage A slice (BN affine + bf16, zero-padded borders)
      const int iy = 2 * oy - 1 + ky, ix = 2 * ox - 1 + kx;
      const bool ok = ((unsigned)iy < (unsigned)Hin) && ((unsigned)ix < (unsigned)Hin);
      alignas(16) unsigned short tmp[16];
      if (ok) {
        const unsigned short* src =
            yin + ((size_t)((b * 64 + e0 + e_l) * Hin * Hin + iy * Hin + ix)) * 64 + ci0;
        uint4 v0 = *(const uint4*)src;
        uint4 v1 = *(const uint4*)(src + 8);
        const unsigned short* h0 = (const unsigned short*)&v0;
        const unsigned short* h1 = (const unsigned short*)&v1;
#pragma unroll
        for (int j = 0; j < 8; ++j) {
          tmp[j]     = f2bf(fmaf(bf2f(h0[j]), s1[ci0 + j],     t1[ci0 + j]));
          tmp[8 + j] = f2bf(fmaf(bf2f(h1[j]), s1[ci0 + 8 + j], t1[ci0 + 8 + j]));
        }
      } else {
#pragma unroll
        for (int j = 0; j < 16; ++j) tmp[j] = 0;
      }
      *(uint4*)&AS[li * 72 + ci0]     = *(uint4*)&tmp[0];
      *(uint4*)&AS[li * 72 + ci0 + 8] = *(uint4*)&tmp[8];
      // stage Bt slice
      const unsigned short* g = wt + ((size_t)b * 9 + s) * 4096;
      const int cout = tid >> 2, cc0 = (tid & 3) * 16;
      uint4 w0 = *(const uint4*)(g + cout * 64 + cc0);
      uint4 w1 = *(const uint4*)(g + cout * 64 + cc0 + 8);
      *(uint4*)&BtS[cout * 72 + cc0]     = w0;
      *(uint4*)&BtS[cout * 72 + cc0 + 8] = w1;
    }
    __syncthreads();
    const unsigned short* ap = &AS[arow * 72 + kq];
    const unsigned short* bp = &BtS[(n0 + (lane & 31)) * 72 + kq];
#pragma unroll
    for (int st = 0; st < 4; ++st) {
      bf16x8 af = *(const bf16x8*)(ap + st * 16);
      bf16x8 bv = *(const bf16x8*)(bp + st * 16);
      acc = __builtin_amdgcn_mfma_f32_32x32x16_bf16(af, bv, acc, 0, 0, 0);
    }
    __syncthreads();
  }

  const int col = n0 + (lane & 31);
  const int rbase = m0 + 4 * (lane >> 5);
  float ls = 0.f, lss = 0.f;
#pragma unroll
  for (int r = 0; r < 16; ++r) {
    const int row = rbase + (r & 3) + 8 * (r >> 2);
    const float v = fmaxf(acc[r], 0.f);
    const int re = row / (Hout * Hout), rp = row % (Hout * Hout);
    yout[((size_t)((b * 64 + e0 + re) * Hout * Hout + rp)) * 64 + col] = f2bf(v);
    ls += v; lss = fmaf(v, v, lss);
  }
  atomicAdd(&redsum[col], ls);
  atomicAdd(&redss[col], lss);
  __syncthreads();
  if (tid < 64) {
    atomicAdd(&statsOut[tid], redsum[tid]);
    atomicAdd(&statsOut[64 + tid], redss[tid]);
  }
}

// ---------------------------------------------------------------------------
// readout: feat = BN(maxpool(y4)), out = feat @ w_ro[b].  One block per task.
// ---------------------------------------------------------------------------
__global__ __launch_bounds__(256) void readout_kernel(
    const unsigned short* __restrict__ y4, const float* __restrict__ w_ro,
    const float* __restrict__ statsIn, float invN, float* __restrict__ outp)
{
  __shared__ float wl[64 * 20];
  __shared__ float feat[64 * 64];
  __shared__ float sArr[64], tArr[64];

  const int b = blockIdx.x, tid = threadIdx.x;

  if (tid < 64) {
    const float m = statsIn[tid] * invN;
    const float var = fmaf(-m, m, statsIn[64 + tid] * invN);
    const float s = rsqrtf(var + BN_EPS);
    sArr[tid] = s; tArr[tid] = -m * s;
  }
  for (int i = tid; i < 1280; i += 256) wl[i] = w_ro[(size_t)b * 1280 + i];
  __syncthreads();

  {
    const int e = tid & 63;
    for (int c = tid >> 6; c < 64; c += 4) {
      const unsigned short* p4 = y4 + ((size_t)(b * 64 + e) * 4) * 64 + c;
      const float v = fmaxf(fmaxf(bf2f(p4[0]), bf2f(p4[64])),
                            fmaxf(bf2f(p4[128]), bf2f(p4[192])));
      feat[c * 64 + e] = fmaf(v, sArr[c], tArr[c]);
    }
  }
  __syncthreads();

  const int e = tid >> 2, og = (tid & 3) * 5;
  float acc[5] = {0.f, 0.f, 0.f, 0.f, 0.f};
  for (int c = 0; c < 64; ++c) {
    const float f = feat[c * 64 + e];
#pragma unroll
    for (int j = 0; j < 5; ++j) acc[j] = fmaf(f, wl[c * 20 + og + j], acc[j]);
  }
#pragma unroll
  for (int j = 0; j < 5; ++j)
    outp[((size_t)b * 64 + e) * 20 + og + j] = acc[j];
}

// ---------------------------------------------------------------------------
extern "C" void kernel_launch(void* const* d_in, const int* in_sizes, int n_in,
                              void* d_out, int out_size, void* d_ws, size_t ws_size,
                              hipStream_t stream) {
  (void)in_sizes; (void)n_in; (void)out_size; (void)ws_size;
  const float* x   = (const float*)d_in[0];
  const float* k1  = (const float*)d_in[1];
  const float* k2  = (const float*)d_in[2];
  const float* k3  = (const float*)d_in[3];
  const float* k4  = (const float*)d_in[4];
  const float* wro = (const float*)d_in[5];
  float* out = (float*)d_out;
  char* ws = (char*)d_ws;

  // ws layout (bytes): stats 2048 | k2t/k3t/k4t 3x4718592 | y2 25690112 |
  // y3 8388608 | y4 2097152   => total ~50.3 MB
  float* stats = (float*)ws;
  unsigned short* k2t = (unsigned short*)(ws + 2048);
  unsigned short* k3t = k2t + (size_t)2359296;
  unsigned short* k4t = k3t + (size_t)2359296;
  unsigned short* y2  = k4t + (size_t)2359296;
  unsigned short* y3  = y2  + (size_t)12845056;
  unsigned short* y4  = y3  + (size_t)4194304;

  hipMemsetAsync(stats, 0, 2048, stream);

  prep_weights_kernel<<<192, 256, 0, stream>>>(k2, k3, k4, k2t, k3t, k4t);
  conv1_stats_kernel<<<4096, 256, 0, stream>>>(x, k1, stats);
  conv2_mfma_kernel<<<4096, 256, 0, stream>>>(
      x, k1, k2t, stats, 1.f / 802816.f, y2, stats + 128);
  conv_mfma_kernel<7, 4, 4><<<1024, 256, 0, stream>>>(
      y2, k3t, stats + 128, 1.f / 200704.f, y3, stats + 256);
  conv_mfma_kernel<4, 2, 16><<<256, 256, 0, stream>>>(
      y3, k4t, stats + 256, 1.f / 65536.f, y4, stats + 384);
  readout_kernel<<<64, 256, 0, stream>>>(y4, wro, stats + 384, 1.f / 16384.f, out);
}

// Round 4
// 268.080 us; speedup vs baseline: 2.9611x; 1.4684x over previous
//
#include <hip/hip_runtime.h>

#define BN_EPS 1e-3f

typedef __attribute__((ext_vector_type(8))) short bf16x8;
typedef __attribute__((ext_vector_type(16))) float floatx16;
typedef unsigned short u16;

__device__ __forceinline__ u16 f2bf(float f) {
  unsigned u = __float_as_uint(f);
  u += 0x7fffu + ((u >> 16) & 1u);   // RNE
  return (u16)(u >> 16);
}
__device__ __forceinline__ float bf2f(u16 h) {
  return __uint_as_float(((unsigned)h) << 16);
}

static constexpr int NSHARD = 256;   // stats shards (128 floats each)

// ---------------------------------------------------------------------------
// conv1: x[be][28][28] * k1[b][9][64] -> y1 bf16 [be][196][64] + sharded
// per-channel sum/sumsq.  Padded 30x30 LDS input -> branch-free inner loop.
// All 64 lanes of a wave share one pixel -> LDS broadcast reads (free).
// ---------------------------------------------------------------------------
__global__ __launch_bounds__(256) void conv1_kernel(
    const float* __restrict__ x, const float* __restrict__ k1,
    u16* __restrict__ y1, float* __restrict__ statsSh)
{
  __shared__ float xp[900];   // 30x30, zero border
  __shared__ float w1[576];
  __shared__ float red[256];

  const int be = blockIdx.x, b = be >> 6, tid = threadIdx.x;

  for (int i = tid; i < 900; i += 256) xp[i] = 0.f;
  for (int i = tid; i < 576; i += 256) w1[i] = k1[(size_t)b * 576 + i];
  __syncthreads();
  for (int i = tid; i < 784; i += 256) {
    const int r = i / 28, cc = i - 28 * r;
    xp[(r + 1) * 30 + (cc + 1)] = x[(size_t)be * 784 + i];
  }
  __syncthreads();

  const int c = tid & 63;
  float wr[9];
#pragma unroll
  for (int t = 0; t < 9; ++t) wr[t] = w1[t * 64 + c];

  float sum = 0.f, ss = 0.f;
  for (int pix = tid >> 6; pix < 196; pix += 4) {
    const int oy = pix / 14, ox = pix - 14 * oy;
    const float* xb = &xp[(2 * oy) * 30 + 2 * ox];  // (iy+1,ix+1) with iy=2oy-1+ky
    float acc = 0.f;
#pragma unroll
    for (int ky = 0; ky < 3; ++ky)
#pragma unroll
      for (int kx = 0; kx < 3; ++kx)
        acc = fmaf(xb[ky * 30 + kx], wr[ky * 3 + kx], acc);
    const float v = fmaxf(acc, 0.f);
    y1[((size_t)be * 196 + pix) * 64 + c] = f2bf(v);
    sum += v;
    ss = fmaf(v, v, ss);
  }

  red[tid] = sum;
  __syncthreads();
  if (tid < 64)
    atomicAdd(&statsSh[(blockIdx.x & (NSHARD - 1)) * 128 + tid],
              red[tid] + red[tid + 64] + red[tid + 128] + red[tid + 192]);
  __syncthreads();
  red[tid] = ss;
  __syncthreads();
  if (tid < 64)
    atomicAdd(&statsSh[(blockIdx.x & (NSHARD - 1)) * 128 + 64 + tid],
              red[tid] + red[tid + 64] + red[tid + 128] + red[tid + 192]);
}

// ---------------------------------------------------------------------------
// fold: reduce prev-layer stats shards -> s,t; emit Wf bf16 [b][9][cout][cin]
// scaled by s_cin, and 9-class boundary bias table bias[b][cls][cout]
// (cls = ry*3+rx; ry/rx: 0=interior, 1=first row/col, 2=last row/col w/ odd Hin).
// One block per task.
// ---------------------------------------------------------------------------
__global__ __launch_bounds__(256) void fold_kernel(
    const float* __restrict__ W, const float* __restrict__ statsSh, float invN,
    u16* __restrict__ Wf, float* __restrict__ biasCls)
{
  __shared__ float T[64 * 68];
  __shared__ float P[256];
  __shared__ float s1[64], t1[64];
  __shared__ float TB[576];

  const int b = blockIdx.x, tid = threadIdx.x;

  // reduce 256 shards x 128 stats
  {
    const int g = tid >> 7, cidx = tid & 127;
    float acc = 0.f;
    for (int k = 0; k < 128; ++k) acc += statsSh[(g * 128 + k) * 128 + cidx];
    P[tid] = acc;
  }
  __syncthreads();
  if (tid < 128) T[tid] = P[tid] + P[tid + 128];
  __syncthreads();
  if (tid < 64) {
    const float m = T[tid] * invN;
    const float var = fmaf(-m, m, T[64 + tid] * invN);
    const float s = rsqrtf(var + BN_EPS);
    s1[tid] = s;
    t1[tid] = -m * s;
  }
  for (int i = tid; i < 576; i += 256) TB[i] = 0.f;
  __syncthreads();

  const int cin = tid >> 2, q0 = (tid & 3) * 16;     // pass 1 mapping
  const int cout = tid >> 2, ci0 = (tid & 3) * 16;   // pass 2 mapping
  for (int s = 0; s < 9; ++s) {
    const float* ss = W + ((size_t)b * 9 + s) * 4096;
#pragma unroll
    for (int q = 0; q < 16; q += 4) {
      const float4 v = *(const float4*)(ss + cin * 64 + q0 + q);
      T[(q0 + q + 0) * 68 + cin] = v.x;
      T[(q0 + q + 1) * 68 + cin] = v.y;
      T[(q0 + q + 2) * 68 + cin] = v.z;
      T[(q0 + q + 3) * 68 + cin] = v.w;
    }
    __syncthreads();
    alignas(16) u16 tmp[16];
    float tb = 0.f;
#pragma unroll
    for (int j = 0; j < 16; ++j) {
      const float wv = T[cout * 68 + ci0 + j];
      tmp[j] = f2bf(wv * s1[ci0 + j]);
      tb = fmaf(t1[ci0 + j], wv, tb);
    }
    u16* dst = Wf + ((size_t)b * 9 + s) * 4096 + cout * 64 + ci0;
    *(uint4*)dst       = *(uint4*)&tmp[0];
    *(uint4*)(dst + 8) = *(uint4*)&tmp[8];
    atomicAdd(&TB[s * 64 + cout], tb);
    __syncthreads();
  }

  for (int idx = tid; idx < 576; idx += 256) {
    const int cls = idx >> 6, cc = idx & 63;
    const int ry = cls / 3, rx = cls % 3;
    float bsum = 0.f;
#pragma unroll
    for (int s = 0; s < 9; ++s) {
      const int ky = s / 3, kx = s % 3;
      const bool valid = !((ry == 1 && ky == 0) || (ry == 2 && ky == 2) ||
                           (rx == 1 && kx == 0) || (rx == 2 && kx == 2));
      if (valid) bsum += TB[s * 64 + cc];
    }
    biasCls[(size_t)b * 576 + idx] = bsum;
  }
}

// ---------------------------------------------------------------------------
// conv_gemm: layers 2..4.  Raw bf16 A/B staging (BN folded into Wf/bias),
// 32x32x16 bf16 MFMA, fp32 bias + ReLU epilogue, bf16 out, sharded stats.
// Block: G examples (M = G*Hout^2 <= 64 rows) x 64 couts, K = 9 x 64.
// ---------------------------------------------------------------------------
template <int Hin, int Hout, int G>
__global__ __launch_bounds__(256) void conv_gemm_kernel(
    const u16* __restrict__ yin, const u16* __restrict__ Wf,
    const float* __restrict__ biasCls, u16* __restrict__ yout,
    float* __restrict__ statsSh)
{
  constexpr int PPI  = Hout * Hout;
  constexpr int ROWS = G * PPI;
  constexpr int BPT  = 64 / G;

  __shared__ __align__(16) u16 AS[64 * 72];
  __shared__ __align__(16) u16 BtS[64 * 72];
  __shared__ float biasS[576];
  __shared__ float redsum[64], redss[64];

  const int b = blockIdx.x / BPT;
  const int e0 = (blockIdx.x % BPT) * G;
  const int tid = threadIdx.x, lane = tid & 63, wave = tid >> 6;

  for (int i = tid; i < 576; i += 256) biasS[i] = biasCls[(size_t)b * 576 + i];
  if (tid < 64) { redsum[tid] = 0.f; redss[tid] = 0.f; }

  // staging mapping: row (A-row / B-cout), 16 channels at ci0
  const int row = tid >> 2, ci0 = (tid & 3) * 16;
  const int e_l = row / PPI, pp = row % PPI;
  const int oy = pp / Hout, ox = pp % Hout;
  const bool rowOk = row < ROWS;
  const size_t inBase = ((size_t)(b * 64 + e0 + e_l)) * (Hin * Hin) * 64;

  const int mi = wave & 1, ni = wave >> 1;
  const int m0 = mi * 32, n0 = ni * 32;
  const int arow = m0 + (lane & 31), kq = (lane >> 5) * 8;

  floatx16 acc;
#pragma unroll
  for (int r = 0; r < 16; ++r) acc[r] = 0.f;

  __syncthreads();

#pragma unroll
  for (int s = 0; s < 9; ++s) {
    const int ky = s / 3, kx = s % 3;
    const int iy = 2 * oy - 1 + ky, ix = 2 * ox - 1 + kx;
    const bool ok = rowOk && ((unsigned)iy < (unsigned)Hin) &&
                    ((unsigned)ix < (unsigned)Hin);
    uint4 v0 = {0, 0, 0, 0}, v1 = {0, 0, 0, 0};
    if (ok) {
      const u16* src = yin + inBase + (size_t)(iy * Hin + ix) * 64 + ci0;
      v0 = *(const uint4*)src;
      v1 = *(const uint4*)(src + 8);
    }
    *(uint4*)&AS[row * 72 + ci0]     = v0;
    *(uint4*)&AS[row * 72 + ci0 + 8] = v1;
    {
      const u16* g = Wf + ((size_t)b * 9 + s) * 4096 + row * 64 + ci0;
      *(uint4*)&BtS[row * 72 + ci0]     = *(const uint4*)g;
      *(uint4*)&BtS[row * 72 + ci0 + 8] = *(const uint4*)(g + 8);
    }
    __syncthreads();
    const u16* ap = &AS[arow * 72 + kq];
    const u16* bp = &BtS[(n0 + (lane & 31)) * 72 + kq];
#pragma unroll
    for (int st = 0; st < 4; ++st) {
      bf16x8 af = *(const bf16x8*)(ap + st * 16);
      bf16x8 bv = *(const bf16x8*)(bp + st * 16);
      acc = __builtin_amdgcn_mfma_f32_32x32x16_bf16(af, bv, acc, 0, 0, 0);
    }
    __syncthreads();
  }

  // epilogue: bias by boundary class, ReLU, bf16 store, stats
  const int col = n0 + (lane & 31);
  const int rbase = m0 + 4 * (lane >> 5);
  float ls = 0.f, lss = 0.f;
#pragma unroll
  for (int r = 0; r < 16; ++r) {
    const int rw = rbase + (r & 3) + 8 * (r >> 2);
    if (rw < ROWS) {
      const int re = rw / PPI, pr = rw % PPI;
      const int ooy = pr / Hout, oox = pr % Hout;
      const int ry = (ooy == 0) ? 1 : ((2 * ooy + 1 >= Hin) ? 2 : 0);
      const int rx = (oox == 0) ? 1 : ((2 * oox + 1 >= Hin) ? 2 : 0);
      const float v = fmaxf(acc[r] + biasS[(ry * 3 + rx) * 64 + col], 0.f);
      yout[((size_t)(b * 64 + e0 + re) * PPI + pr) * 64 + col] = f2bf(v);
      ls += v;
      lss = fmaf(v, v, lss);
    }
  }
  atomicAdd(&redsum[col], ls);
  atomicAdd(&redss[col], lss);
  __syncthreads();
  if (tid < 64) {
    const int sh = blockIdx.x & (NSHARD - 1);
    atomicAdd(&statsSh[sh * 128 + tid], redsum[tid]);
    atomicAdd(&statsSh[sh * 128 + 64 + tid], redss[tid]);
  }
}

// ---------------------------------------------------------------------------
// readout: reduce stats4 shards, feat = BN(maxpool(y4)), out = feat @ w_ro[b].
// ---------------------------------------------------------------------------
__global__ __launch_bounds__(256) void readout_kernel(
    const u16* __restrict__ y4, const float* __restrict__ w_ro,
    const float* __restrict__ statsSh, float invN, float* __restrict__ outp)
{
  __shared__ float wl[64 * 20];
  __shared__ float feat[64 * 64];
  __shared__ float P[256];
  __shared__ float sArr[64], tArr[64];

  const int b = blockIdx.x, tid = threadIdx.x;

  {
    const int g = tid >> 7, cidx = tid & 127;
    float acc = 0.f;
    for (int k = 0; k < 128; ++k) acc += statsSh[(g * 128 + k) * 128 + cidx];
    P[tid] = acc;
  }
  for (int i = tid; i < 1280; i += 256) wl[i] = w_ro[(size_t)b * 1280 + i];
  __syncthreads();
  if (tid < 64) {
    const float m = (P[tid] + P[tid + 128]) * invN;
    const float var = fmaf(-m, m, (P[64 + tid] + P[192 + tid]) * invN);
    const float s = rsqrtf(var + BN_EPS);
    sArr[tid] = s;
    tArr[tid] = -m * s;
  }
  __syncthreads();

  {
    const int e = tid & 63;
    for (int c = tid >> 6; c < 64; c += 4) {
      const u16* p4 = y4 + ((size_t)(b * 64 + e) * 4) * 64 + c;
      const float v = fmaxf(fmaxf(bf2f(p4[0]), bf2f(p4[64])),
                            fmaxf(bf2f(p4[128]), bf2f(p4[192])));
      feat[c * 64 + e] = fmaf(v, sArr[c], tArr[c]);
    }
  }
  __syncthreads();

  const int e = tid >> 2, og = (tid & 3) * 5;
  float acc[5] = {0.f, 0.f, 0.f, 0.f, 0.f};
  for (int c = 0; c < 64; ++c) {
    const float f = feat[c * 64 + e];
#pragma unroll
    for (int j = 0; j < 5; ++j) acc[j] = fmaf(f, wl[c * 20 + og + j], acc[j]);
  }
#pragma unroll
  for (int j = 0; j < 5; ++j)
    outp[((size_t)b * 64 + e) * 20 + og + j] = acc[j];
}

// ---------------------------------------------------------------------------
extern "C" void kernel_launch(void* const* d_in, const int* in_sizes, int n_in,
                              void* d_out, int out_size, void* d_ws, size_t ws_size,
                              hipStream_t stream) {
  (void)in_sizes; (void)n_in; (void)out_size; (void)ws_size;
  const float* x   = (const float*)d_in[0];
  const float* k1  = (const float*)d_in[1];
  const float* k2  = (const float*)d_in[2];
  const float* k3  = (const float*)d_in[3];
  const float* k4  = (const float*)d_in[4];
  const float* wro = (const float*)d_in[5];
  float* out = (float*)d_out;
  char* ws = (char*)d_ws;

  // ws layout (bytes), total ~143.6 MB:
  //  stats   4 layers x 256 shards x 128 f32 = 524288
  //  k2f/k3f/k4f bf16                         3 x 4718592
  //  bias2/3/4  64 x 576 f32                  3 x 147456
  //  y2 bf16 [4096][49][64]                   25690112
  //  y1 bf16 [4096][196][64]                  102760448  (y3/y4 alias into y1
  //                                            after conv2: y1 dead then)
  float* stats = (float*)ws;                            // 4*32768 floats
  u16* k2f = (u16*)(ws + 524288);
  u16* k3f = k2f + (size_t)2359296;
  u16* k4f = k3f + (size_t)2359296;
  float* bias2 = (float*)(ws + 524288 + 3 * (size_t)4718592);
  float* bias3 = bias2 + 36864;
  float* bias4 = bias3 + 36864;
  u16* y2 = (u16*)((char*)(bias4 + 36864));
  u16* y1 = y2 + (size_t)12845056;
  u16* y3 = y1;                      // alias: y1 dead after conv2
  u16* y4 = y3 + (size_t)4194304;

  float* st1 = stats;
  float* st2 = stats + 32768;
  float* st3 = stats + 65536;
  float* st4 = stats + 98304;

  hipMemsetAsync(stats, 0, 524288, stream);

  conv1_kernel<<<4096, 256, 0, stream>>>(x, k1, y1, st1);
  fold_kernel<<<64, 256, 0, stream>>>(k2, st1, 1.f / 802816.f, k2f, bias2);
  conv_gemm_kernel<14, 7, 1><<<4096, 256, 0, stream>>>(y1, k2f, bias2, y2, st2);
  fold_kernel<<<64, 256, 0, stream>>>(k3, st2, 1.f / 200704.f, k3f, bias3);
  conv_gemm_kernel<7, 4, 4><<<1024, 256, 0, stream>>>(y2, k3f, bias3, y3, st3);
  fold_kernel<<<64, 256, 0, stream>>>(k4, st3, 1.f / 65536.f, k4f, bias4);
  conv_gemm_kernel<4, 2, 16><<<256, 256, 0, stream>>>(y3, k4f, bias4, y4, st4);
  readout_kernel<<<64, 256, 0, stream>>>(y4, wro, st4, 1.f / 16384.f, out);
}